// Round 4
// baseline (444.275 us; speedup 1.0000x reference)
//
#include <hip/hip_runtime.h>

// LSTM: B=4096, T=2048, I=4, H=3, gates i,f,g,o (W rows r = g*3 + u)
// R7: distributed-h dot + hoisted stores. Model (R4-R6 data): step = ~15
//     serial chain stages x ~15cy dep-latency (1 wave/SIMD; VALUBusy 23%
//     says issue is NOT the limit). Levers = chain stages.
//     - a' = S1 + sum_k D_k*r2_k with S1 = xacc' + sum wh_k*go_k and
//       D_k = -2*wh_k*go_k computed in the exp2(cc) trans shadow. Post-r2
//       chain = gather + fma-tree (4 stages) vs 5 through myh. myh now only
//       feeds the store (off-cycle).
//     - stores buffered in regs, one predicated block per 8 steps (one exec
//       dance per tb instead of per step).
// R6: tree h-dot, o-fold, raw stores + len-based tail zero (kept).
// R5 lesson: per-wave in-order issue; extra instrs between dependent ops add.
// R4 lesson: cross-lane pipe choice ~free; stages matter.

#define BB 4096
#define TT 2048
#define L2E 1.4426950408889634f

template<int CTRL>
__device__ __forceinline__ float dppf(float v) {
    return __int_as_float(
        __builtin_amdgcn_update_dpp(0, __float_as_int(v), CTRL, 0xF, 0xF, true));
}

__global__ __launch_bounds__(64, 1) void lstm_seq(
    const float* __restrict__ x, const float* __restrict__ Wih,
    const float* __restrict__ Whh, const float* __restrict__ bih,
    const float* __restrict__ bhh, const int* __restrict__ len,
    float* __restrict__ out)
{
    const int lane  = threadIdx.x & 63;
    const int s     = lane & 3;          // gate: 0=i,1=f,2=g,3=o
    const int q     = (lane >> 2) & 3;   // quad = unit (3 = dup of unit 2)
    const int row16 = lane >> 4;         // sequence within wave (4 per wave)
    const int b     = blockIdx.x * 4 + row16;
    const int u     = (q < 3) ? q : 2;
    const int wrow  = s * 3 + u;

    // r = rcp(1+exp2(a)), a = pre*scale:
    //   sigmoid (s!=2): scale=-log2e,  act = r
    //   tanh    (s==2): scale=+2log2e, act = 2L2E - 4L2E*r  (pre-scaled g)
    // Cell carried as cc = 2*log2e*c; tanh(c) = 1 - 2*rcp(1+exp2(cc)).
    const float scale = (s == 2) ? (2.f * L2E) : (-L2E);
    const float Aa = (s == 2) ? (2.f * L2E) : 0.f;
    const float Bb = (s == 2) ? (-4.f * L2E) : 1.f;

    const float xw0 = Wih[wrow * 4 + 0] * scale;
    const float xw1 = Wih[wrow * 4 + 1] * scale;
    const float xw2 = Wih[wrow * 4 + 2] * scale;
    const float xw3 = Wih[wrow * 4 + 3] * scale;
    const float bias = (bih[wrow] + bhh[wrow]) * scale;

    // h slot j arrives via row_ror:(4j): source quad (q - j) & 3.
    // Zero weight for the dup-quad source (keeps dup bit-synced to unit 2).
    float wh[4];
    #pragma unroll
    for (int j = 0; j < 4; ++j) {
        const int srcq = (q - j) & 3;
        wh[j] = (srcq == 3) ? 0.f : Whh[wrow * 3 + srcq] * scale;
    }

    const int mylen = len[b];
    int wmax = mylen;
    #pragma unroll
    for (int off = 1; off < 64; off <<= 1)
        wmax = max(wmax, __shfl_xor(wmax, off));
    const int Tloop = (wmax + 7) & ~7;

    const float4* __restrict__ xrow = ((const float4*)x) + (size_t)b * TT;
    float* __restrict__ orow = out + (size_t)b * (TT * 3);
    const bool writer = (s == 0) && (q < 3);

    float4 buf[8];
    #pragma unroll
    for (int uu = 0; uu < 8; ++uu) buf[uu] = xrow[uu];

    // State: cc, r2p (prev tanh-rcp), go (prev o-gate), and the prebuilt
    // S1/D for the upcoming step. t=0: h=0 -> D=0, S1 = xproj(t=0).
    float cc = 0.f, r2p = 0.f, go = 0.f;
    float D0 = 0.f, D1 = 0.f, D2 = 0.f, D3 = 0.f;
    float S1;
    {
        const float4 xv = buf[0];
        S1 = fmaf(xw3, xv.w, fmaf(xw2, xv.z,
             fmaf(xw1, xv.y, fmaf(xw0, xv.x, bias))));
    }

    for (int tb = 0; tb < Tloop; tb += 8) {
        float xacc[8];
        #pragma unroll
        for (int uu = 1; uu < 8; ++uu) {   // [0] consumed by prev block's S1
            const float4 xv = buf[uu];
            xacc[uu] = fmaf(xw3, xv.w, fmaf(xw2, xv.z,
                       fmaf(xw1, xv.y, fmaf(xw0, xv.x, bias))));
        }
        #pragma unroll
        for (int uu = 0; uu < 8; ++uu) {
            const int tn = tb + 8 + uu;
            buf[uu] = xrow[tn < TT ? tn : 0];
        }
        float msave[8];
        #pragma unroll
        for (int uu = 0; uu < 8; ++uu) {
            // --- on-chain: a = S1 + sum_k D_k * r2_k ---
            const float R1 = dppf<0x124>(r2p);   // row_ror:4  -> quad q-1
            const float R2 = dppf<0x128>(r2p);   // row_ror:8  -> quad q-2
            const float R3 = dppf<0x12C>(r2p);   // row_ror:12 -> quad q-3
            const float e0  = fmaf(D0, r2p, S1);
            const float u01 = fmaf(D1, R1, e0);
            const float m2v = D2 * R2;
            const float u23 = fmaf(D3, R3, m2v);
            const float a   = u01 + u23;
            const float r   = __builtin_amdgcn_rcpf(1.f + __builtin_amdgcn_exp2f(a));
            const float act = fmaf(Bb, r, Aa);
            const float gi = dppf<0x00>(act);
            const float gf = dppf<0x55>(act);
            const float gg = dppf<0xAA>(act);   // pre-scaled tanh
            go = dppf<0xFF>(act);
            cc = fmaf(gf, cc, gi * gg);          // cc = 2L2E * c
            const float e2 = __builtin_amdgcn_exp2f(cc);
            // --- off-chain (trans shadow): next step's S1/D from go ---
            const float G1 = dppf<0x124>(go);
            const float G2 = dppf<0x128>(go);
            const float G3 = dppf<0x12C>(go);
            const float P0 = wh[0] * go;
            const float P1 = wh[1] * G1;
            const float P2 = wh[2] * G2;
            const float P3 = wh[3] * G3;
            float xn;
            if (uu < 7) {
                xn = xacc[uu + 1];
            } else {                              // next block's step 0
                const float4 xv = buf[0];
                xn = fmaf(xw3, xv.w, fmaf(xw2, xv.z,
                     fmaf(xw1, xv.y, fmaf(xw0, xv.x, bias))));
            }
            S1 = xn + ((P0 + P1) + (P2 + P3));
            D0 = -2.f * P0; D1 = -2.f * P1; D2 = -2.f * P2; D3 = -2.f * P3;
            const float n2go = -2.f * go;
            // --- chain continues ---
            const float r2 = __builtin_amdgcn_rcpf(1.f + e2);
            msave[uu] = fmaf(n2go, r2, go);       // o*tanh(c), store-only
            r2p = r2;
        }
        if (writer) {
            #pragma unroll
            for (int uu = 0; uu < 8; ++uu)
                orow[(tb + uu) * 3 + q] = msave[uu];
        }
    }

    // Order main-loop stores before tail overwrites (same addresses).
    asm volatile("s_waitcnt vmcnt(0)" ::: "memory");

    // Zero t in [len[row], TT) for this wave's 4 rows.
    #pragma unroll
    for (int rr = 0; rr < 4; ++rr) {
        const int bb = blockIdx.x * 4 + rr;
        const int L  = len[bb];
        float* __restrict__ ob = out + (size_t)bb * (TT * 3);
        const int s0 = L * 3;                 // first float to zero
        const int a4 = (s0 + 3) & ~3;         // align up to float4
        if (lane < a4 - s0) ob[s0 + lane] = 0.f;
        float4* __restrict__ o4 = (float4*)ob;
        for (int idx = a4 / 4 + lane; idx < TT * 3 / 4; idx += 64)
            o4[idx] = make_float4(0.f, 0.f, 0.f, 0.f);
    }
}

extern "C" void kernel_launch(void* const* d_in, const int* in_sizes, int n_in,
                              void* d_out, int out_size, void* d_ws, size_t ws_size,
                              hipStream_t stream) {
    const float* x    = (const float*)d_in[0];
    const float* Wih  = (const float*)d_in[1];
    const float* Whh  = (const float*)d_in[2];
    const float* bih  = (const float*)d_in[3];
    const float* bhh  = (const float*)d_in[4];
    const int*   lenp = (const int*)d_in[5];
    float* out = (float*)d_out;

    lstm_seq<<<BB / 4, 64, 0, stream>>>(x, Wih, Whh, bih, bhh, lenp, out);
}

// Round 5
// 408.184 us; speedup vs baseline: 1.0884x; 1.0884x over previous
//
#include <hip/hip_runtime.h>

// LSTM: B=4096, T=2048, I=4, H=3, gates i,f,g,o (W rows r = g*3 + u)
// R8: R6 base (best, 243us) + fused-DPP arithmetic via inline asm to cut 2
//     chain stages WITHOUT adding instructions (R7 lesson: off-chain instrs
//     add ~2cy each at 1 wave/SIMD; only stage removal pays).
//     - dot: A=fmac(xacc,myh,wh0); A=fmac_dpp(A,ror4 myh,wh1) ||
//            B=mul_dpp(ror8 myh,wh2); B=fmac_dpp(B,ror12 myh,wh3); a=A+B
//       depth 3 (was: mov_dpp gather + fma tree, depth 4), 5 instrs (was 8).
//     - cc:  fc=mul_dpp(qp1(act),cc) || mp=mul_dpp(qp0(act),act);
//            cc=fmac_dpp(fc, qp2(mp), 1.0)   [qp2(mp) = gi*gg from g-lane]
//       act->cc in 2 stages (was bcast+mul+fma = 3), 4 instrs (was 6).
//     DPP wait-states (VALU-write -> DPP-read = 2cy) handled by s_nop INSIDE
//     the asm (hazard recognizer can't see into asm blocks).
// R6: tree h-dot, o-fold, raw stores + len-based tail zero (kept verbatim).
// Chain now 13 stages: {A,B}(1) {A',B'}(2) a(3) exp2(4) +1(5) rcp(6) act(7)
//   {fc,mp,go}(8) cc(9) exp2(10) +1(11) rcp(12) myh(13).

#define BB 4096
#define TT 2048
#define L2E 1.4426950408889634f

__global__ __launch_bounds__(64, 1) void lstm_seq(
    const float* __restrict__ x, const float* __restrict__ Wih,
    const float* __restrict__ Whh, const float* __restrict__ bih,
    const float* __restrict__ bhh, const int* __restrict__ len,
    float* __restrict__ out)
{
    const int lane  = threadIdx.x & 63;
    const int s     = lane & 3;          // gate: 0=i,1=f,2=g,3=o
    const int q     = (lane >> 2) & 3;   // quad = unit (3 = dup of unit 2)
    const int row16 = lane >> 4;         // sequence within wave (4 per wave)
    const int b     = blockIdx.x * 4 + row16;
    const int u     = (q < 3) ? q : 2;
    const int wrow  = s * 3 + u;

    // r = rcp(1+exp2(a)), a = pre*scale:
    //   sigmoid (s!=2): scale=-log2e,  act = r
    //   tanh    (s==2): scale=+2log2e, act = 2L2E - 4L2E*r  (pre-scaled g)
    // Cell carried as cc = 2*log2e*c; tanh(c) = 1 - 2*rcp(1+exp2(cc)).
    const float scale = (s == 2) ? (2.f * L2E) : (-L2E);
    const float Aa = (s == 2) ? (2.f * L2E) : 0.f;
    const float Bb = (s == 2) ? (-4.f * L2E) : 1.f;

    const float xw0 = Wih[wrow * 4 + 0] * scale;
    const float xw1 = Wih[wrow * 4 + 1] * scale;
    const float xw2 = Wih[wrow * 4 + 2] * scale;
    const float xw3 = Wih[wrow * 4 + 3] * scale;
    const float bias = (bih[wrow] + bhh[wrow]) * scale;

    // h slot j arrives via row_ror:(4j): source quad (q - j) & 3.
    // Zero weight for the dup-quad source (keeps dup bit-synced to unit 2).
    float wh[4];
    #pragma unroll
    for (int j = 0; j < 4; ++j) {
        const int srcq = (q - j) & 3;
        wh[j] = (srcq == 3) ? 0.f : Whh[wrow * 3 + srcq] * scale;
    }

    const int mylen = len[b];
    int wmax = mylen;
    #pragma unroll
    for (int off = 1; off < 64; off <<= 1)
        wmax = max(wmax, __shfl_xor(wmax, off));
    const int Tloop = (wmax + 7) & ~7;

    float myh = 0.f, cc = 0.f;
    const float fone = 1.0f;             // VOP2 src1 must be a VGPR
    const float4* __restrict__ xrow = ((const float4*)x) + (size_t)b * TT;
    float* __restrict__ orow = out + (size_t)b * (TT * 3);
    const bool writer = (s == 0) && (q < 3);

    float4 buf[8];
    float xacc[8];
    #pragma unroll
    for (int uu = 0; uu < 8; ++uu) buf[uu] = xrow[uu];

    for (int tb = 0; tb < Tloop; tb += 8) {
        #pragma unroll
        for (int uu = 0; uu < 8; ++uu) {
            const float4 xv = buf[uu];
            xacc[uu] = fmaf(xw3, xv.w, fmaf(xw2, xv.z,
                       fmaf(xw1, xv.y, fmaf(xw0, xv.x, bias))));
        }
        #pragma unroll
        for (int uu = 0; uu < 8; ++uu) {
            const int tn = tb + 8 + uu;
            buf[uu] = xrow[tn < TT ? tn : 0];
        }
        #pragma unroll
        for (int uu = 0; uu < 8; ++uu) {
            const int t = tb + uu;
            // --- h-dot, fused-DPP, depth 3 ---
            // A = xacc + wh0*myh + wh1*ror4(myh)
            // B = wh2*ror8(myh) + wh3*ror12(myh);  a = A + B
            float A = xacc[uu];
            float Bv;
            asm("v_fmac_f32 %[A], %[h], %[w0]\n\t"
                "s_nop 0\n\t"
                "v_mul_f32_dpp %[B], %[h], %[w2] row_ror:8 row_mask:0xf bank_mask:0xf\n\t"
                "v_fmac_f32_dpp %[A], %[h], %[w1] row_ror:4 row_mask:0xf bank_mask:0xf\n\t"
                "v_fmac_f32_dpp %[B], %[h], %[w3] row_ror:12 row_mask:0xf bank_mask:0xf"
                : [A] "+v"(A), [B] "=&v"(Bv)
                : [h] "v"(myh), [w0] "v"(wh[0]), [w1] "v"(wh[1]),
                  [w2] "v"(wh[2]), [w3] "v"(wh[3]));
            const float a = A + Bv;
            const float r = __builtin_amdgcn_rcpf(1.f + __builtin_amdgcn_exp2f(a));
            const float act = fmaf(Bb, r, Aa);
            // --- broadcast + cc, fused-DPP, act->cc in 2 stages ---
            // fc = qp1(act)*cc (= gf*cc);  mp = qp0(act)*act (g-lane: gi*gg)
            // cc = fc + qp2(mp)*1.0;       go = qp3(act)
            float fcv, mpv, gov;
            asm("s_nop 1\n\t"
                "v_mul_f32_dpp %[fc], %[act], %[cc] quad_perm:[1,1,1,1] row_mask:0xf bank_mask:0xf\n\t"
                "v_mul_f32_dpp %[mp], %[act], %[act] quad_perm:[0,0,0,0] row_mask:0xf bank_mask:0xf\n\t"
                "v_mov_b32_dpp %[go], %[act] quad_perm:[3,3,3,3] row_mask:0xf bank_mask:0xf\n\t"
                "s_nop 0\n\t"
                "v_fmac_f32_dpp %[fc], %[mp], %[one] quad_perm:[2,2,2,2] row_mask:0xf bank_mask:0xf"
                : [fc] "=&v"(fcv), [mp] "=&v"(mpv), [go] "=&v"(gov)
                : [act] "v"(act), [cc] "v"(cc), [one] "v"(fone));
            cc = fcv;                              // cc = gf*cc + gi*gg (2L2E-scaled)
            const float e2 = __builtin_amdgcn_exp2f(cc);
            const float n2go = -2.f * gov;         // cheap, off-chain
            const float r2 = __builtin_amdgcn_rcpf(1.f + e2);
            myh = fmaf(n2go, r2, gov);             // o * tanh(c)
            if (writer) orow[t * 3 + q] = myh;     // raw; tail zeroes t >= len
        }
    }

    // Order main-loop stores before tail overwrites (same addresses).
    asm volatile("s_waitcnt vmcnt(0)" ::: "memory");

    // Zero t in [len[row], TT) for this wave's 4 rows.
    #pragma unroll
    for (int rr = 0; rr < 4; ++rr) {
        const int bb = blockIdx.x * 4 + rr;
        const int L  = len[bb];
        float* __restrict__ ob = out + (size_t)bb * (TT * 3);
        const int s0 = L * 3;                 // first float to zero
        const int a4 = (s0 + 3) & ~3;         // align up to float4
        if (lane < a4 - s0) ob[s0 + lane] = 0.f;
        float4* __restrict__ o4 = (float4*)ob;
        for (int idx = a4 / 4 + lane; idx < TT * 3 / 4; idx += 64)
            o4[idx] = make_float4(0.f, 0.f, 0.f, 0.f);
    }
}

extern "C" void kernel_launch(void* const* d_in, const int* in_sizes, int n_in,
                              void* d_out, int out_size, void* d_ws, size_t ws_size,
                              hipStream_t stream) {
    const float* x    = (const float*)d_in[0];
    const float* Wih  = (const float*)d_in[1];
    const float* Whh  = (const float*)d_in[2];
    const float* bih  = (const float*)d_in[3];
    const float* bhh  = (const float*)d_in[4];
    const int*   lenp = (const int*)d_in[5];
    float* out = (float*)d_out;

    lstm_seq<<<BB / 4, 64, 0, stream>>>(x, Wih, Whh, bih, bhh, lenp, out);
}